// Round 9
// baseline (1070.197 us; speedup 1.0000x reference)
//
#include <hip/hip_runtime.h>
#include <float.h>
#include <stdint.h>

#define IN_DIM 1433
#define HID 16
#define OUTD 7

// gemm1 geometry: persistent blocks, 64-row panels, K-tiles of 128
#define BR 64
#define KT 128
#define NTI 12                       // ceil(1433/128)
#define KLASTI 25                    // 1433 - 11*128
#define WLN (IN_DIM * HID)           // 22928 floats

#define AS1 __attribute__((address_space(1)))
#define AS3 __attribute__((address_space(3)))

// ---------------- GEMM1: xw1[N][16] = feat[N][1433] @ W1[1433][16] -------------
// 1024 threads = 16 waves, persistent (grid=256), 157 KB LDS:
//   wl[22928]  = W1 transposed to [q][k][4]  (91.7 KB, loaded once per block)
//   xs[2][64*128] double-buffered x tiles     (64 KB)
// KEY FIX vs R8: compute phase is VMEM-FREE (W1 comes from LDS broadcast), so
// the next-tile DMA prefetch is not drained by in-order vmcnt waits of W1
// loads -- compute(i) truly overlaps DMA(i+1); the only drain is the tile
// barrier. Tile rows are 512-B segments (vs 128-B in R8).
// Swizzle (both sides, rule #21): float4-block b of row r stored at slot
// (b&~7)|((b&7)^(r&7)) via pre-swizzled GLOBAL source; read applies same XOR.
__global__ __launch_bounds__(1024, 1) void gemm1_kernel(
    const float* __restrict__ feat, const float* __restrict__ W1,
    float* __restrict__ xw1, int N, int NPAN)
{
    __shared__ float wl[WLN];            // 91712 B
    __shared__ float xs[2][BR * KT];     // 2 * 32768 B
    const int t = threadIdx.x;
    const int lane = t & 63;
    const int w = t >> 6;                // wave 0..15

    // ---- one-time: preload W1 transposed: wl[q*5732 + k*4 + e] = W1[k][4q+e]
    for (int i = t; i < WLN / 4; i += 1024) {    // i indexes float4s of W1
        const float4 v = ((const float4*)W1)[i];
        const int k = i >> 2;
        const int q = i & 3;
        float* d = wl + q * (IN_DIM * 4) + k * 4;
        d[0] = v.x; d[1] = v.y; d[2] = v.z; d[3] = v.w;
    }
    __syncthreads();

    const int r   = t & 63;              // row owned for compute
    const int rx8 = r & 7;
    const int q   = (t >> 6) & 3;        // output quad (wave-uniform)
    const int h   = t >> 8;              // k-quarter 0..3
    const long maxElem = (long)N * IN_DIM - 1;
    const float* __restrict__ wq = wl + q * (IN_DIM * 4);

    for (int pan = blockIdx.x; pan < NPAN; pan += gridDim.x) {
        const int row0 = pan * BR;
        float acc0 = 0.f, acc1 = 0.f, acc2 = 0.f, acc3 = 0.f;

        // stage one 64x128 tile: 8 width-4 DMA instrs/wave, each = 1 row-half
        auto stage = [&](int buf, int k0) {
#pragma unroll
            for (int i = 0; i < 8; ++i) {
                const int ri   = w * 4 + (i >> 1);
                const int half = i & 1;
                const int fl   = half * 64 + lane;     // float slot in row
                const int b    = fl >> 2, e = fl & 3;
                const int gcol = (((b & ~7) | ((b & 7) ^ (ri & 7))) << 2) | e;
                long elem = (long)(row0 + ri) * IN_DIM + k0 + gcol;
                if (elem > maxElem) elem = maxElem;    // tail clamp
                __builtin_amdgcn_global_load_lds(
                    (const AS1 void*)(feat + elem),
                    (AS3 void*)(&xs[buf][ri * KT + half * 64]), 4, 0, 0);
            }
        };

        auto compute = [&](int buf, int k0, int klen) {
            const int kb = h * 32;
            int kl = klen - kb; if (kl > 32) kl = 32; if (kl < 0) kl = 0;
            const float* xrow = &xs[buf][r * KT];
#pragma unroll 8
            for (int kk = 0; kk + 4 <= kl; kk += 4) {
                const int bk = (kb + kk) >> 2;
                const int sl = (bk & ~7) | ((bk & 7) ^ rx8);
                const float4 xv = *(const float4*)&xrow[sl << 2];
                const float* wp = wq + (size_t)(k0 + kb + kk) * 4;
                const float4 w0 = *(const float4*)(wp);
                const float4 w1 = *(const float4*)(wp + 4);
                const float4 w2 = *(const float4*)(wp + 8);
                const float4 w3 = *(const float4*)(wp + 12);
                acc0 += xv.x * w0.x; acc1 += xv.x * w0.y;
                acc2 += xv.x * w0.z; acc3 += xv.x * w0.w;
                acc0 += xv.y * w1.x; acc1 += xv.y * w1.y;
                acc2 += xv.y * w1.z; acc3 += xv.y * w1.w;
                acc0 += xv.z * w2.x; acc1 += xv.z * w2.y;
                acc2 += xv.z * w2.z; acc3 += xv.z * w2.w;
                acc0 += xv.w * w3.x; acc1 += xv.w * w3.y;
                acc2 += xv.w * w3.z; acc3 += xv.w * w3.w;
            }
            for (int kk = kl & ~3; kk < kl; ++kk) {    // tail (last tile only)
                const int k = kb + kk;
                const int bk = k >> 2;
                const int sl = (bk & ~7) | ((bk & 7) ^ rx8);
                const float x = xrow[(sl << 2) | (k & 3)];
                const float* wp = wq + (size_t)(k0 + k) * 4;
                acc0 += x * wp[0]; acc1 += x * wp[1];
                acc2 += x * wp[2]; acc3 += x * wp[3];
            }
        };

        stage(0, 0);
        __syncthreads();                       // tile 0 resident
        for (int it = 0; it < NTI - 1; ++it) {
            stage((it + 1) & 1, (it + 1) * KT);    // DMA prefetch next tile
            compute(it & 1, it * KT, KT);          // VMEM-free compute
            __syncthreads();                       // tile boundary drain
        }
        compute((NTI - 1) & 1, (NTI - 1) * KT, KLASTI);

        // reduce the 4 k-quarters (scratch in xs[0], free after tile NTI-2)
        if (h) {
            float* s = &xs[0][((h - 1) * 256 + (t & 255)) * 4];
            s[0] = acc0; s[1] = acc1; s[2] = acc2; s[3] = acc3;
        }
        __syncthreads();
        if (h == 0) {
#pragma unroll
            for (int u = 0; u < 3; ++u) {
                const float* s = &xs[0][(u * 256 + t) * 4];
                acc0 += s[0]; acc1 += s[1]; acc2 += s[2]; acc3 += s[3];
            }
            const int grow = row0 + r;
            if (grow < N)
                *(float4*)(xw1 + (size_t)grow * HID + q * 4) =
                    make_float4(acc0, acc1, acc2, acc3);
        }
        __syncthreads();    // protect scratch/xs before next panel's stage
    }
}

// ---------------- CSR build: histogram -> scan -> counting-sort fill ----------
__global__ __launch_bounds__(256) void hist_kernel(
    const int* __restrict__ dst, int* __restrict__ cnt, int E)
{
    const int e = blockIdx.x * 256 + threadIdx.x;
    if (e < E) atomicAdd(&cnt[dst[e]], 1);
}

__global__ __launch_bounds__(256) void scan1_kernel(
    const int* __restrict__ cnt, int* __restrict__ offs,
    int* __restrict__ bsum, int N)
{
    __shared__ int lds[256];
    const int t = threadIdx.x, b = blockIdx.x;
    const int base = b * 1024 + t * 4;
    int c0 = 0, c1 = 0, c2 = 0, c3 = 0;
    if (base + 0 < N) c0 = cnt[base + 0];
    if (base + 1 < N) c1 = cnt[base + 1];
    if (base + 2 < N) c2 = cnt[base + 2];
    if (base + 3 < N) c3 = cnt[base + 3];
    const int s = c0 + c1 + c2 + c3;
    lds[t] = s;
    __syncthreads();
    for (int off = 1; off < 256; off <<= 1) {
        int v = (t >= off) ? lds[t - off] : 0;
        __syncthreads();
        lds[t] += v;
        __syncthreads();
    }
    const int excl = lds[t] - s;
    if (t == 255) bsum[b] = lds[255];
    int run = excl;
    if (base + 0 < N) { offs[base + 0] = run; run += c0; }
    if (base + 1 < N) { offs[base + 1] = run; run += c1; }
    if (base + 2 < N) { offs[base + 2] = run; run += c2; }
    if (base + 3 < N) { offs[base + 3] = run; run += c3; }
}

__global__ __launch_bounds__(256) void scan2_kernel(
    const int* __restrict__ bsum, int* __restrict__ bbase, int NB)
{
    __shared__ int lds[256];
    const int t = threadIdx.x;
    const int v = (t < NB) ? bsum[t] : 0;
    lds[t] = v;
    __syncthreads();
    for (int off = 1; off < 256; off <<= 1) {
        int u = (t >= off) ? lds[t - off] : 0;
        __syncthreads();
        lds[t] += u;
        __syncthreads();
    }
    bbase[t] = lds[t] - v;
}

__global__ __launch_bounds__(256) void scan3_kernel(
    int* __restrict__ offs, int* __restrict__ cursor,
    const int* __restrict__ bbase, int N, int E)
{
    const int t = threadIdx.x, b = blockIdx.x;
    const int add = bbase[b];
    const int base = b * 1024 + t * 4;
#pragma unroll
    for (int i = 0; i < 4; ++i) {
        const int idx = base + i;
        if (idx < N) {
            const int v = offs[idx] + add;
            offs[idx] = v;
            cursor[idx] = v;
        }
    }
    if (b == 0 && t == 0) offs[N] = E;
}

__global__ __launch_bounds__(256) void fill_kernel(
    const int* __restrict__ src, const int* __restrict__ dst,
    const float* __restrict__ a, int* __restrict__ cursor,
    uint2* __restrict__ pairs, int E)
{
    const int e = blockIdx.x * 256 + threadIdx.x;
    if (e >= E) return;
    const int d = dst[e];
    const int pos = atomicAdd(&cursor[d], 1);
    pairs[pos] = make_uint2((unsigned)src[e], __float_as_uint(a[e]));
}

// ------- gather1: agg = sum(a*xw1[src]) ; fused h=relu(agg+b1); xw2 = h@W2 ----
__global__ __launch_bounds__(256) void gather1_kernel(
    const uint2* __restrict__ pairs, const int* __restrict__ offs,
    const float* __restrict__ xw1, const float* __restrict__ b1,
    const float* __restrict__ W2, float* __restrict__ xw2, int N)
{
    __shared__ float w2s[HID * OUTD];
    const int t = threadIdx.x;
    if (t < HID * OUTD) w2s[t] = W2[t];
    __syncthreads();
    const int lane = t & 63;
    const int r = blockIdx.x * 4 + (t >> 6);
    if (r >= N) return;
    const int g = lane >> 2;
    const int c = lane & 3;
    const int start = offs[r], end = offs[r + 1];
    float4 acc = make_float4(0.f, 0.f, 0.f, 0.f);
    int e = start + g;
    for (; e + 16 < end; e += 32) {
        const uint2 p0 = pairs[e];
        const uint2 p1 = pairs[e + 16];
        const float4 v0 = *(const float4*)(xw1 + (size_t)p0.x * HID + c * 4);
        const float4 v1 = *(const float4*)(xw1 + (size_t)p1.x * HID + c * 4);
        const float a0 = __uint_as_float(p0.y);
        const float a1 = __uint_as_float(p1.y);
        acc.x += a0 * v0.x + a1 * v1.x;
        acc.y += a0 * v0.y + a1 * v1.y;
        acc.z += a0 * v0.z + a1 * v1.z;
        acc.w += a0 * v0.w + a1 * v1.w;
    }
    if (e < end) {
        const uint2 p0 = pairs[e];
        const float4 v0 = *(const float4*)(xw1 + (size_t)p0.x * HID + c * 4);
        const float a0 = __uint_as_float(p0.y);
        acc.x += a0 * v0.x; acc.y += a0 * v0.y;
        acc.z += a0 * v0.z; acc.w += a0 * v0.w;
    }
#pragma unroll
    for (int m = 4; m < 64; m <<= 1) {
        acc.x += __shfl_xor(acc.x, m);
        acc.y += __shfl_xor(acc.y, m);
        acc.z += __shfl_xor(acc.z, m);
        acc.w += __shfl_xor(acc.w, m);
    }
    const float4 b1v = ((const float4*)b1)[c];
    float4 hv;
    hv.x = fmaxf(acc.x + b1v.x, 0.f);
    hv.y = fmaxf(acc.y + b1v.y, 0.f);
    hv.z = fmaxf(acc.z + b1v.z, 0.f);
    hv.w = fmaxf(acc.w + b1v.w, 0.f);
    float hh[16];
#pragma unroll
    for (int cc = 0; cc < 4; ++cc) {
        hh[cc * 4 + 0] = __shfl(hv.x, cc);
        hh[cc * 4 + 1] = __shfl(hv.y, cc);
        hh[cc * 4 + 2] = __shfl(hv.z, cc);
        hh[cc * 4 + 3] = __shfl(hv.w, cc);
    }
    const int col = (lane & 7) < OUTD ? (lane & 7) : 0;
    float sacc = 0.f;
#pragma unroll
    for (int j = 0; j < HID; ++j) sacc += hh[j] * w2s[j * OUTD + col];
    if (lane < 8) xw2[(size_t)r * 8 + lane] = (lane < OUTD) ? sacc : 0.f;
}

// ------- gather2: o = sum(a*xw2[src]) + b2 ; fused log_softmax -> out ---------
__global__ __launch_bounds__(256) void gather2_kernel(
    const uint2* __restrict__ pairs, const int* __restrict__ offs,
    const float* __restrict__ xw2, const float* __restrict__ b2,
    float* __restrict__ out, int N)
{
    const int t = threadIdx.x;
    const int lane = t & 63;
    const int r = blockIdx.x * 4 + (t >> 6);
    if (r >= N) return;
    const int g = lane >> 1;
    const int c = lane & 1;
    const int start = offs[r], end = offs[r + 1];
    float4 acc = make_float4(0.f, 0.f, 0.f, 0.f);
    for (int e = start + g; e < end; e += 32) {
        const uint2 p = pairs[e];
        const float4 v = *(const float4*)(xw2 + (size_t)p.x * 8 + c * 4);
        const float a = __uint_as_float(p.y);
        acc.x += a * v.x; acc.y += a * v.y;
        acc.z += a * v.z; acc.w += a * v.w;
    }
#pragma unroll
    for (int m = 2; m < 64; m <<= 1) {
        acc.x += __shfl_xor(acc.x, m);
        acc.y += __shfl_xor(acc.y, m);
        acc.z += __shfl_xor(acc.z, m);
        acc.w += __shfl_xor(acc.w, m);
    }
    float4 x;
    if (c == 0) {
        const float4 b2v = *(const float4*)b2;
        x.x = acc.x + b2v.x; x.y = acc.y + b2v.y;
        x.z = acc.z + b2v.z; x.w = acc.w + b2v.w;
    } else {
        x.x = acc.x + b2[4]; x.y = acc.y + b2[5];
        x.z = acc.z + b2[6]; x.w = -FLT_MAX;
    }
    float mymax = fmaxf(fmaxf(x.x, x.y), x.z);
    if (c == 0) mymax = fmaxf(mymax, x.w);
    const float m = fmaxf(mymax, __shfl_xor(mymax, 1));
    float es = expf(x.x - m) + expf(x.y - m) + expf(x.z - m);
    if (c == 0) es += expf(x.w - m);
    const float s = es + __shfl_xor(es, 1);
    const float lg = logf(s);
    float* op = out + (size_t)r * OUTD;
    if (c == 0) {
        op[0] = x.x - m - lg; op[1] = x.y - m - lg;
        op[2] = x.z - m - lg; op[3] = x.w - m - lg;
    } else {
        op[4] = x.x - m - lg; op[5] = x.y - m - lg;
        op[6] = x.z - m - lg;
    }
}

extern "C" void kernel_launch(void* const* d_in, const int* in_sizes, int n_in,
                              void* d_out, int out_size, void* d_ws, size_t ws_size,
                              hipStream_t stream)
{
    const float* feat  = (const float*)d_in[0];
    const int*   esrc  = (const int*)d_in[1];
    const int*   edst  = (const int*)d_in[2];
    const float* avals = (const float*)d_in[3];
    const float* W1    = (const float*)d_in[4];
    const float* b1    = (const float*)d_in[5];
    const float* W2    = (const float*)d_in[6];
    const float* b2    = (const float*)d_in[7];
    float* out = (float*)d_out;

    const int N = in_sizes[0] / IN_DIM;   // 150000
    const int E = in_sizes[1];            // 4800000
    const int NB = (N + 1023) / 1024;     // 147 (<=256 for scan2)
    const int NPAN = (N + BR - 1) / BR;   // 2344 panels

    // workspace layout
    char* p = (char*)d_ws;
    float* xw1   = (float*)p; p += (size_t)N * HID * sizeof(float);
    float* xw2   = (float*)p; p += (size_t)N * 8 * sizeof(float);
    int*   cnt   = (int*)p;   p += (size_t)N * sizeof(int);
    int*   offs  = (int*)p;   p += (size_t)(N + 1) * sizeof(int);
    int*   cursor= (int*)p;   p += (size_t)N * sizeof(int);
    int*   bsum  = (int*)p;   p += 256 * sizeof(int);
    int*   bbase = (int*)p;   p += 256 * sizeof(int);
    p = (char*)(((uintptr_t)p + 15) & ~(uintptr_t)15);
    uint2* pairs = (uint2*)p;

    hipMemsetAsync(cnt, 0, (size_t)N * sizeof(int), stream);

    gemm1_kernel<<<256, 1024, 0, stream>>>(feat, W1, xw1, N, NPAN);

    hist_kernel<<<(E + 255) / 256, 256, 0, stream>>>(edst, cnt, E);
    scan1_kernel<<<NB, 256, 0, stream>>>(cnt, offs, bsum, N);
    scan2_kernel<<<1, 256, 0, stream>>>(bsum, bbase, NB);
    scan3_kernel<<<NB, 256, 0, stream>>>(offs, cursor, bbase, N, E);
    fill_kernel<<<(E + 255) / 256, 256, 0, stream>>>(esrc, edst, avals, cursor, pairs, E);

    gather1_kernel<<<(N + 3) / 4, 256, 0, stream>>>(pairs, offs, xw1, b1, W2, xw2, N);
    gather2_kernel<<<(N + 3) / 4, 256, 0, stream>>>(pairs, offs, xw2, b2, out, N);
}